// Round 3
// baseline (282.651 us; speedup 1.0000x reference)
//
#include <hip/hip_runtime.h>
#include <math.h>

#define NN   1024
#define FF   32
#define HID  64
#define OUTF 32

// ws layout (float offsets)
#define WS_A   0                       // 1024*64
#define WS_B   (WS_A + NN*HID)         // 65536
#define WS_W2  (WS_B + NN*HID)         // 131072  (OUT x HID row-major)
#define WS_B1  (WS_W2 + OUTF*HID)      // 133120
#define WS_B2  (WS_B1 + HID)           // 133184
#define WS_C4  (WS_B2 + 64)            // 133248  (N x 4: x,y,z,0)
// total = 137344 floats = 549 KB

__device__ __forceinline__ float swish(float x) {
    // x * sigmoid(x); exp(-x) = exp2(-x*log2e). v_exp/v_rcp ~1ulp: abs err ~1e-5 max
    float e = __builtin_amdgcn_exp2f(x * -1.442695040888963f);
    return x * __builtin_amdgcn_rcpf(1.0f + e);
}

__global__ void prep_kernel(
    const float* __restrict__ Coords,
    const float* __restrict__ Emb,
    const float* __restrict__ W1,
    const float* __restrict__ b1,
    const float* __restrict__ W2,
    const float* __restrict__ b2,
    float* __restrict__ ws)
{
    const int b = blockIdx.x;
    const int t = threadIdx.x;
    if (b < NN) {
        // A[b][t] = sum_f Emb[b,f]*W1[t,f];  B[b][t] = sum_f Emb[b,f]*W1[t,F+f]
        float accA = 0.f, accB = 0.f;
        const float* w1row = W1 + t * (2 * FF);
        const float* erow  = Emb + b * FF;
        #pragma unroll
        for (int f = 0; f < FF; ++f) {
            float e = erow[f];
            accA = fmaf(e, w1row[f],      accA);
            accB = fmaf(e, w1row[FF + f], accB);
        }
        ws[WS_A + b * HID + t] = accA;
        ws[WS_B + b * HID + t] = accB;
    } else {
        #pragma unroll 1
        for (int k = t; k < OUTF * HID; k += 64) ws[WS_W2 + k] = W2[k];
        if (t < HID)  ws[WS_B1 + t] = b1[t];
        if (t < OUTF) ws[WS_B2 + t] = b2[t];
        #pragma unroll 1
        for (int n = t; n < NN; n += 64) {
            ws[WS_C4 + n * 4 + 0] = Coords[n * 3 + 0];
            ws[WS_C4 + n * 4 + 1] = Coords[n * 3 + 1];
            ws[WS_C4 + n * 4 + 2] = Coords[n * 3 + 2];
            ws[WS_C4 + n * 4 + 3] = 0.f;
        }
    }
}

// One wave per (i, 64-j tile); lane owns one (i,j) pair end to end.
__global__ __launch_bounds__(64) void main_kernel(
    const float* __restrict__ Edges,
    const float* __restrict__ ws,
    float* __restrict__ out)
{
    const int i = blockIdx.y;
    const int j = blockIdx.x * 64 + threadIdx.x;

    const float* __restrict__ Ai  = ws + WS_A + i * HID;   // wave-uniform
    const float* __restrict__ Bj  = ws + WS_B + j * HID;   // per-lane
    const float* __restrict__ W2f = ws + WS_W2;            // wave-uniform
    const float* __restrict__ b1f = ws + WS_B1;            // wave-uniform
    const float* __restrict__ b2f = ws + WS_B2;            // wave-uniform

    // w = Edges[i,j] * ||C_i - C_j||
    const float4 ci = *(const float4*)(ws + WS_C4 + i * 4);
    const float4 cj = *(const float4*)(ws + WS_C4 + j * 4);
    const float dx = ci.x - cj.x, dy = ci.y - cj.y, dz = ci.z - cj.z;
    const float dist = sqrtf(dx * dx + dy * dy + dz * dz);
    const float w = Edges[i * NN + j] * dist;

    // h1[h] = swish(w*(A_i[h]+B_j[h]) + b1[h]) held in VGPRs
    float h1r[HID];
    #pragma unroll
    for (int h = 0; h < HID; h += 4) {
        const float4 bv  = *(const float4*)(Bj + h);
        const float4 av  = *(const float4*)(Ai + h);
        const float4 b1v = *(const float4*)(b1f + h);
        h1r[h + 0] = swish(fmaf(w, av.x + bv.x, b1v.x));
        h1r[h + 1] = swish(fmaf(w, av.y + bv.y, b1v.y));
        h1r[h + 2] = swish(fmaf(w, av.z + bv.z, b1v.z));
        h1r[h + 3] = swish(fmaf(w, av.w + bv.w, b1v.w));
    }

    // pre2[o] = h1 . W2[o,:] + b2[o]; out = swish(pre2), f32 stores
    float* __restrict__ outd = out + (size_t)(i * NN + j) * OUTF;

    #pragma unroll 1
    for (int og = 0; og < 4; ++og) {
        float acc[8];
        #pragma unroll
        for (int q = 0; q < 8; ++q) {
            const float* __restrict__ w2row = W2f + (og * 8 + q) * HID; // uniform
            float a = b2f[og * 8 + q];
            #pragma unroll
            for (int h = 0; h < HID; ++h)
                a = fmaf(h1r[h], w2row[h], a);
            acc[q] = a;
        }
        float4 v0, v1;
        v0.x = swish(acc[0]); v0.y = swish(acc[1]);
        v0.z = swish(acc[2]); v0.w = swish(acc[3]);
        v1.x = swish(acc[4]); v1.y = swish(acc[5]);
        v1.z = swish(acc[6]); v1.w = swish(acc[7]);
        *(float4*)(outd + og * 8 + 0) = v0;
        *(float4*)(outd + og * 8 + 4) = v1;
    }
}

extern "C" void kernel_launch(void* const* d_in, const int* in_sizes, int n_in,
                              void* d_out, int out_size, void* d_ws, size_t ws_size,
                              hipStream_t stream)
{
    const float* Edges  = (const float*)d_in[0];
    const float* Coords = (const float*)d_in[1];
    const float* Emb    = (const float*)d_in[2];
    const float* W1     = (const float*)d_in[3];
    const float* b1     = (const float*)d_in[4];
    const float* W2     = (const float*)d_in[5];
    const float* b2     = (const float*)d_in[6];
    float* ws = (float*)d_ws;
    float* out = (float*)d_out;

    hipLaunchKernelGGL(prep_kernel, dim3(NN + 1), dim3(64), 0, stream,
                       Coords, Emb, W1, b1, W2, b2, ws);
    hipLaunchKernelGGL(main_kernel, dim3(NN / 64, NN), dim3(64), 0, stream,
                       Edges, ws, out);
}

// Round 4
// 200.666 us; speedup vs baseline: 1.4086x; 1.4086x over previous
//
#include <hip/hip_runtime.h>
#include <math.h>

#define NN   1024
#define FF   32
#define HID  64
#define OUTF 32

typedef unsigned int  uint;
typedef unsigned short ushort;
typedef __attribute__((ext_vector_type(8)))  __bf16 bf16x8;
typedef __attribute__((ext_vector_type(16))) float  floatx16;

// ws layout (float offsets)
#define WS_A    0                      // N*HID
#define WS_B    (WS_A + NN*HID)        // 65536
#define WS_C4   (WS_B + NN*HID)        // 131072  (N x 4: x,y,z,0)
#define WS_B1   (WS_C4 + NN*4)         // 135168
#define WS_B2   (WS_B1 + HID)          // 135232 (pad to 64)
#define WS_W2H  (WS_B2 + 64)           // 135296  ushort[4*64*8] = 1024 floats
#define WS_W2L  (WS_W2H + 1024)        // 136320  ushort[4*64*8]
// total = 137344 floats = 549 KB

union FragU { ushort u[8]; bf16x8 v; };

__device__ __forceinline__ float swish(float x) {
    // x * sigmoid(x); v_exp_f32 / v_rcp_f32, abs err ~1e-5 max — far under budget
    float e = __builtin_amdgcn_exp2f(x * -1.442695040888963f);
    return x * __builtin_amdgcn_rcpf(1.0f + e);
}

__global__ void prep_kernel(
    const float* __restrict__ Coords,
    const float* __restrict__ Emb,
    const float* __restrict__ W1,
    const float* __restrict__ b1,
    const float* __restrict__ W2,
    const float* __restrict__ b2,
    float* __restrict__ ws)
{
    const int b = blockIdx.x;
    const int t = threadIdx.x;
    if (b < NN) {
        // A[b][t] = sum_f Emb[b,f]*W1[t,f];  B[b][t] = sum_f Emb[b,f]*W1[t,F+f]
        float accA = 0.f, accB = 0.f;
        const float* w1row = W1 + t * (2 * FF);
        const float* erow  = Emb + b * FF;
        #pragma unroll
        for (int f = 0; f < FF; ++f) {
            float e = erow[f];
            accA = fmaf(e, w1row[f],      accA);
            accB = fmaf(e, w1row[FF + f], accB);
        }
        ws[WS_A + b * HID + t] = accA;
        ws[WS_B + b * HID + t] = accB;
    } else {
        if (t < HID)  ws[WS_B1 + t] = b1[t];
        if (t < OUTF) ws[WS_B2 + t] = b2[t];
        #pragma unroll 1
        for (int n = t; n < NN; n += 64) {
            ws[WS_C4 + n * 4 + 0] = Coords[n * 3 + 0];
            ws[WS_C4 + n * 4 + 1] = Coords[n * 3 + 1];
            ws[WS_C4 + n * 4 + 2] = Coords[n * 3 + 2];
            ws[WS_C4 + n * 4 + 3] = 0.f;
        }
        // W2^T fragments in MFMA B-layout (32x32x16): n = t&31, k = (t>>5)*8 + j
        // split into truncated-bf16 hi + lo so the GEMM is f32-exact
        ushort* w2h = (ushort*)(ws + WS_W2H);
        ushort* w2l = (ushort*)(ws + WS_W2L);
        const int n  = t & 31;
        const int kh = (t >> 5) * 8;
        #pragma unroll
        for (int c = 0; c < 4; ++c) {
            #pragma unroll
            for (int j = 0; j < 8; ++j) {
                const int k = c * 16 + kh + j;
                const float v = W2[n * HID + k];
                const uint  x = __float_as_uint(v);
                const float lo = v - __uint_as_float(x & 0xffff0000u);
                w2h[(c * 64 + t) * 8 + j] = (ushort)(x >> 16);
                w2l[(c * 64 + t) * 8 + j] = (ushort)(__float_as_uint(lo) >> 16);
            }
        }
    }
}

// Block = 256 thr = 4 waves. Wave handles 32 pairs (fixed i) via 32x32x16 MFMA:
// M = 32 pairs, N = 32 outs, K = 64 hid (4 chunks of 16).
// Lane L: pair p = L&31, hid-slice k = c*16 + (L>>5)*8 + j  (== A-fragment layout)
__global__ __launch_bounds__(256) void main_kernel(
    const float* __restrict__ Edges,
    const float* __restrict__ ws,
    float* __restrict__ out)
{
    const int lane = threadIdx.x & 63;
    const int wave = threadIdx.x >> 6;
    const int i    = blockIdx.y;
    const int j0   = blockIdx.x * 128 + wave * 32;
    const int p    = lane & 31;
    const int half = lane >> 5;
    const int jp   = j0 + p;

    // w = Edges[i,jp] * ||C_i - C_jp||
    const float4 ci = *(const float4*)(ws + WS_C4 + i * 4);
    const float4 cj = *(const float4*)(ws + WS_C4 + jp * 4);
    const float dx = ci.x - cj.x, dy = ci.y - cj.y, dz = ci.z - cj.z;
    const float dist = sqrtf(dx * dx + dy * dy + dz * dz);
    const float w = Edges[i * NN + jp] * dist;

    // W2 fragments (per-lane, L1-resident)
    const ushort* w2hp = (const ushort*)(ws + WS_W2H);
    const ushort* w2lp = (const ushort*)(ws + WS_W2L);
    bf16x8 bh[4], bl[4];
    #pragma unroll
    for (int c = 0; c < 4; ++c) {
        bh[c] = *(const bf16x8*)(w2hp + (c * 64 + lane) * 8);
        bl[c] = *(const bf16x8*)(w2lp + (c * 64 + lane) * 8);
    }

    // layer-1 + swish in f32, split h1 into truncated bf16 hi+lo (exact residual)
    const float* __restrict__ Ai  = ws + WS_A + i * HID;
    const float* __restrict__ Bj  = ws + WS_B + jp * HID;
    const float* __restrict__ b1f = ws + WS_B1;
    FragU ah[4], al[4];
    #pragma unroll
    for (int c = 0; c < 4; ++c) {
        const int h0 = c * 16 + half * 8;
        float av[8], bv[8], cv[8];
        *(float4*)(av + 0) = *(const float4*)(Ai + h0);
        *(float4*)(av + 4) = *(const float4*)(Ai + h0 + 4);
        *(float4*)(bv + 0) = *(const float4*)(Bj + h0);
        *(float4*)(bv + 4) = *(const float4*)(Bj + h0 + 4);
        *(float4*)(cv + 0) = *(const float4*)(b1f + h0);
        *(float4*)(cv + 4) = *(const float4*)(b1f + h0 + 4);
        #pragma unroll
        for (int j = 0; j < 8; ++j) {
            const float pre = fmaf(w, av[j] + bv[j], cv[j]);
            const float h1  = swish(pre);
            const uint  x   = __float_as_uint(h1);
            const float lo  = h1 - __uint_as_float(x & 0xffff0000u);
            ah[c].u[j] = (ushort)(x >> 16);
            al[c].u[j] = (ushort)(__float_as_uint(lo) >> 16);
        }
    }

    // layer-2 GEMM: pre2 = (h1_hi + h1_lo) @ W2hi^T + h1_hi @ W2lo^T  (12 MFMAs)
    floatx16 acc = {0.f,0.f,0.f,0.f,0.f,0.f,0.f,0.f,0.f,0.f,0.f,0.f,0.f,0.f,0.f,0.f};
    #pragma unroll
    for (int c = 0; c < 4; ++c) {
        acc = __builtin_amdgcn_mfma_f32_32x32x16_bf16(ah[c].v, bh[c], acc, 0, 0, 0);
        acc = __builtin_amdgcn_mfma_f32_32x32x16_bf16(al[c].v, bh[c], acc, 0, 0, 0);
        acc = __builtin_amdgcn_mfma_f32_32x32x16_bf16(ah[c].v, bl[c], acc, 0, 0, 0);
    }

    // epilogue: C/D layout n = lane&31, m = (r&3) + 8*(r>>2) + 4*half
    // each half-wave dword store covers one full 128-B line
    const float b2n = ws[WS_B2 + p];
    float* __restrict__ ob = out + ((size_t)i * NN + j0) * OUTF + p;
    #pragma unroll
    for (int r = 0; r < 16; ++r) {
        const int m = (r & 3) + 8 * (r >> 2) + 4 * half;
        ob[m * OUTF] = swish(acc[r] + b2n);
    }
}

extern "C" void kernel_launch(void* const* d_in, const int* in_sizes, int n_in,
                              void* d_out, int out_size, void* d_ws, size_t ws_size,
                              hipStream_t stream)
{
    const float* Edges  = (const float*)d_in[0];
    const float* Coords = (const float*)d_in[1];
    const float* Emb    = (const float*)d_in[2];
    const float* W1     = (const float*)d_in[3];
    const float* b1     = (const float*)d_in[4];
    const float* W2     = (const float*)d_in[5];
    const float* b2     = (const float*)d_in[6];
    float* ws  = (float*)d_ws;
    float* out = (float*)d_out;

    hipLaunchKernelGGL(prep_kernel, dim3(NN + 1), dim3(64), 0, stream,
                       Coords, Emb, W1, b1, W2, b2, ws);
    hipLaunchKernelGGL(main_kernel, dim3(NN / 128, NN), dim3(256), 0, stream,
                       Edges, ws, out);
}

// Round 5
// 193.650 us; speedup vs baseline: 1.4596x; 1.0362x over previous
//
#include <hip/hip_runtime.h>
#include <math.h>

#define NN   1024
#define FF   32
#define HID  64
#define OUTF 32
#define ITER 4

typedef unsigned int  uint;
typedef unsigned short ushort;
typedef __attribute__((ext_vector_type(8)))  __bf16 bf16x8;
typedef __attribute__((ext_vector_type(16))) float  floatx16;

// ws layout (float offsets)
#define WS_A    0                      // N*HID
#define WS_B    (WS_A + NN*HID)        // 65536
#define WS_C4   (WS_B + NN*HID)        // 131072  (N x 4: x,y,z,0)
#define WS_B1   (WS_C4 + NN*4)         // 135168
#define WS_B2   (WS_B1 + HID)          // 135232 (pad to 64)
#define WS_W2H  (WS_B2 + 64)           // 135296  ushort[4*64*8] = 1024 floats
#define WS_W2L  (WS_W2H + 1024)        // 136320  ushort[4*64*8]
// total = 137344 floats = 549 KB

union FragU { ushort u[8]; bf16x8 v; };

__device__ __forceinline__ float swish(float x) {
    // x * sigmoid(x); v_exp_f32 / v_rcp_f32, abs err ~1e-5 max — far under budget
    float e = __builtin_amdgcn_exp2f(x * -1.442695040888963f);
    return x * __builtin_amdgcn_rcpf(1.0f + e);
}

__global__ void prep_kernel(
    const float* __restrict__ Coords,
    const float* __restrict__ Emb,
    const float* __restrict__ W1,
    const float* __restrict__ b1,
    const float* __restrict__ W2,
    const float* __restrict__ b2,
    float* __restrict__ ws)
{
    const int b = blockIdx.x;
    const int t = threadIdx.x;
    if (b < NN) {
        // A[b][t] = sum_f Emb[b,f]*W1[t,f];  B[b][t] = sum_f Emb[b,f]*W1[t,F+f]
        float accA = 0.f, accB = 0.f;
        const float* w1row = W1 + t * (2 * FF);
        const float* erow  = Emb + b * FF;
        #pragma unroll
        for (int f = 0; f < FF; ++f) {
            float e = erow[f];
            accA = fmaf(e, w1row[f],      accA);
            accB = fmaf(e, w1row[FF + f], accB);
        }
        ws[WS_A + b * HID + t] = accA;
        ws[WS_B + b * HID + t] = accB;
    } else {
        if (t < HID)  ws[WS_B1 + t] = b1[t];
        if (t < OUTF) ws[WS_B2 + t] = b2[t];
        #pragma unroll 1
        for (int n = t; n < NN; n += 64) {
            ws[WS_C4 + n * 4 + 0] = Coords[n * 3 + 0];
            ws[WS_C4 + n * 4 + 1] = Coords[n * 3 + 1];
            ws[WS_C4 + n * 4 + 2] = Coords[n * 3 + 2];
            ws[WS_C4 + n * 4 + 3] = 0.f;
        }
        // W2^T fragments in MFMA B-layout (32x32x16): n = t&31, k = (t>>5)*8 + j
        // split into truncated-bf16 hi + lo so the GEMM is f32-exact
        ushort* w2h = (ushort*)(ws + WS_W2H);
        ushort* w2l = (ushort*)(ws + WS_W2L);
        const int n  = t & 31;
        const int kh = (t >> 5) * 8;
        #pragma unroll
        for (int c = 0; c < 4; ++c) {
            #pragma unroll
            for (int j = 0; j < 8; ++j) {
                const int k = c * 16 + kh + j;
                const float v = W2[n * HID + k];
                const uint  x = __float_as_uint(v);
                const float lo = v - __uint_as_float(x & 0xffff0000u);
                w2h[(c * 64 + t) * 8 + j] = (ushort)(x >> 16);
                w2l[(c * 64 + t) * 8 + j] = (ushort)(__float_as_uint(lo) >> 16);
            }
        }
    }
}

// Block = 256 thr = 4 waves. Wave owns a fixed 32-j tile and loops over ITER i's.
// 32x32x16 MFMA: M = 32 pairs (j), N = 32 outs, K = 64 hid (4 chunks of 16).
// Lane L: pair p = L&31, hid-slice k = c*16 + (L>>5)*8 + jj  (== A-fragment layout)
// All j-side invariants (Bj, b1, W2 frags, cj, b2) live in VGPRs across the i-loop;
// per-iteration A_i row comes in through SGPRs (wave-uniform s_load).
__global__ __launch_bounds__(256) void main_kernel(
    const float* __restrict__ Edges,
    const float* __restrict__ ws,
    float* __restrict__ out)
{
    const int lane = threadIdx.x & 63;
    const int wave = threadIdx.x >> 6;
    const int j0   = blockIdx.x * 128 + wave * 32;
    const int i0   = blockIdx.y * ITER;
    const int p    = lane & 31;
    const int half = lane >> 5;
    const int jp   = j0 + p;

    // ---- loop-invariant state (VGPRs) ----
    // W2 fragments
    const ushort* w2hp = (const ushort*)(ws + WS_W2H);
    const ushort* w2lp = (const ushort*)(ws + WS_W2L);
    bf16x8 bh[4], bl[4];
    #pragma unroll
    for (int c = 0; c < 4; ++c) {
        bh[c] = *(const bf16x8*)(w2hp + (c * 64 + lane) * 8);
        bl[c] = *(const bf16x8*)(w2lp + (c * 64 + lane) * 8);
    }
    // Bj + b1 slices at this lane's (half, c) hid positions
    const float* __restrict__ Bj  = ws + WS_B + jp * HID;
    const float* __restrict__ b1f = ws + WS_B1;
    float bv[4][8], b1v[4][8];
    #pragma unroll
    for (int c = 0; c < 4; ++c) {
        const int h0 = c * 16 + half * 8;
        *(float4*)(&bv[c][0])  = *(const float4*)(Bj + h0);
        *(float4*)(&bv[c][4])  = *(const float4*)(Bj + h0 + 4);
        *(float4*)(&b1v[c][0]) = *(const float4*)(b1f + h0);
        *(float4*)(&b1v[c][4]) = *(const float4*)(b1f + h0 + 4);
    }
    const float4 cj  = *(const float4*)(ws + WS_C4 + jp * 4);
    const float  b2n = ws[WS_B2 + p];

    // ---- i loop ----
    #pragma unroll 1
    for (int it = 0; it < ITER; ++it) {
        const int i = i0 + it;

        // wave-uniform scalars
        const float cix = ws[WS_C4 + i * 4 + 0];
        const float ciy = ws[WS_C4 + i * 4 + 1];
        const float ciz = ws[WS_C4 + i * 4 + 2];
        const float dx = cix - cj.x, dy = ciy - cj.y, dz = ciz - cj.z;
        const float dist = sqrtf(dx * dx + dy * dy + dz * dz);
        const float w = Edges[(size_t)i * NN + jp] * dist;

        const float* __restrict__ Ai = ws + WS_A + (size_t)i * HID; // uniform → s_load

        // layer-1 + swish, split h1 into truncated bf16 hi + exact-residual lo
        FragU ah[4], al[4];
        #pragma unroll
        for (int c = 0; c < 4; ++c) {
            #pragma unroll
            for (int jj = 0; jj < 8; ++jj) {
                const float s_lo = Ai[c * 16 + jj];       // SGPR
                const float s_hi = Ai[c * 16 + 8 + jj];   // SGPR
                const float av   = half ? s_hi : s_lo;    // v_cndmask
                const float pre  = fmaf(w, av + bv[c][jj], b1v[c][jj]);
                const float h1   = swish(pre);
                const uint  x    = __float_as_uint(h1);
                const float lo   = h1 - __uint_as_float(x & 0xffff0000u);
                ah[c].u[jj] = (ushort)(x >> 16);
                al[c].u[jj] = (ushort)(__float_as_uint(lo) >> 16);
            }
        }

        // layer-2 GEMM: pre2 = (h1_hi + h1_lo) @ W2hi^T + h1_hi @ W2lo^T
        floatx16 acc = {0.f,0.f,0.f,0.f,0.f,0.f,0.f,0.f,
                        0.f,0.f,0.f,0.f,0.f,0.f,0.f,0.f};
        #pragma unroll
        for (int c = 0; c < 4; ++c) {
            acc = __builtin_amdgcn_mfma_f32_32x32x16_bf16(ah[c].v, bh[c], acc, 0, 0, 0);
            acc = __builtin_amdgcn_mfma_f32_32x32x16_bf16(al[c].v, bh[c], acc, 0, 0, 0);
            acc = __builtin_amdgcn_mfma_f32_32x32x16_bf16(ah[c].v, bl[c], acc, 0, 0, 0);
        }

        // epilogue: C/D layout n = lane&31, m = (r&3) + 8*(r>>2) + 4*half
        // nontemporal: 134 MB streaming writes must not evict the L2 working set
        float* __restrict__ ob = out + ((size_t)i * NN + j0) * OUTF + p;
        #pragma unroll
        for (int r = 0; r < 16; ++r) {
            const int m = (r & 3) + 8 * (r >> 2) + 4 * half;
            __builtin_nontemporal_store(swish(acc[r] + b2n), ob + m * OUTF);
        }
    }
}

extern "C" void kernel_launch(void* const* d_in, const int* in_sizes, int n_in,
                              void* d_out, int out_size, void* d_ws, size_t ws_size,
                              hipStream_t stream)
{
    const float* Edges  = (const float*)d_in[0];
    const float* Coords = (const float*)d_in[1];
    const float* Emb    = (const float*)d_in[2];
    const float* W1     = (const float*)d_in[3];
    const float* b1     = (const float*)d_in[4];
    const float* W2     = (const float*)d_in[5];
    const float* b2     = (const float*)d_in[6];
    float* ws  = (float*)d_ws;
    float* out = (float*)d_out;

    hipLaunchKernelGGL(prep_kernel, dim3(NN + 1), dim3(64), 0, stream,
                       Coords, Emb, W1, b1, W2, b2, ws);
    hipLaunchKernelGGL(main_kernel, dim3(NN / 128, NN / ITER), dim3(256), 0, stream,
                       Edges, ws, out);
}

// Round 6
// 174.863 us; speedup vs baseline: 1.6164x; 1.1074x over previous
//
#include <hip/hip_runtime.h>
#include <math.h>

#define NN   1024
#define FF   32
#define HID  64
#define OUTF 32
#define ITER 8

typedef unsigned int  uint;
typedef unsigned short ushort;
typedef __attribute__((ext_vector_type(8)))  __bf16 bf16x8;
typedef __attribute__((ext_vector_type(16))) float  floatx16;

// ws layout (float offsets)
#define WS_A    0                      // N*HID
#define WS_B    (WS_A + NN*HID)        // 65536
#define WS_C4   (WS_B + NN*HID)        // 131072  (N x 4: x,y,z,0)
#define WS_B1   (WS_C4 + NN*4)         // 135168
#define WS_B2   (WS_B1 + HID)          // 135232 (pad to 64)
#define WS_W2H  (WS_B2 + 64)           // 135296  ushort[4*64*8] = 1024 floats

union FragU { ushort u[8]; bf16x8 v; };

__device__ __forceinline__ float swish(float x) {
    // x * sigmoid(x); v_exp_f32 / v_rcp_f32, abs err ~1e-5 max — far under budget
    float e = __builtin_amdgcn_exp2f(x * -1.442695040888963f);
    return x * __builtin_amdgcn_rcpf(1.0f + e);
}
__device__ __forceinline__ ushort f2bf_rne(float f) {
    uint x = __float_as_uint(f);
    x += 0x7FFFu + ((x >> 16) & 1u);
    return (ushort)(x >> 16);
}

__global__ void prep_kernel(
    const float* __restrict__ Coords,
    const float* __restrict__ Emb,
    const float* __restrict__ W1,
    const float* __restrict__ b1,
    const float* __restrict__ W2,
    const float* __restrict__ b2,
    float* __restrict__ ws)
{
    const int b = blockIdx.x;
    const int t = threadIdx.x;
    if (b < NN) {
        // A[b][t] = sum_f Emb[b,f]*W1[t,f];  B[b][t] = sum_f Emb[b,f]*W1[t,F+f]
        float accA = 0.f, accB = 0.f;
        const float* w1row = W1 + t * (2 * FF);
        const float* erow  = Emb + b * FF;
        #pragma unroll
        for (int f = 0; f < FF; ++f) {
            float e = erow[f];
            accA = fmaf(e, w1row[f],      accA);
            accB = fmaf(e, w1row[FF + f], accB);
        }
        ws[WS_A + b * HID + t] = accA;
        ws[WS_B + b * HID + t] = accB;
    } else {
        if (t < HID)  ws[WS_B1 + t] = b1[t];
        if (t < OUTF) ws[WS_B2 + t] = b2[t];
        #pragma unroll 1
        for (int n = t; n < NN; n += 64) {
            ws[WS_C4 + n * 4 + 0] = Coords[n * 3 + 0];
            ws[WS_C4 + n * 4 + 1] = Coords[n * 3 + 1];
            ws[WS_C4 + n * 4 + 2] = Coords[n * 3 + 2];
            ws[WS_C4 + n * 4 + 3] = 0.f;
        }
        // W2^T fragments in MFMA B-layout (32x32x16): n = t&31, k = (t>>5)*8 + j
        // RNE-rounded bf16 (2^-9 rel err; lo-residual term dropped in main — see bound)
        ushort* w2h = (ushort*)(ws + WS_W2H);
        const int n  = t & 31;
        const int kh = (t >> 5) * 8;
        #pragma unroll
        for (int c = 0; c < 4; ++c) {
            #pragma unroll
            for (int j = 0; j < 8; ++j) {
                const int k = c * 16 + kh + j;
                w2h[(c * 64 + t) * 8 + j] = f2bf_rne(W2[n * HID + k]);
            }
        }
    }
}

// Block = 256 thr = 4 waves. Wave owns a fixed 32-j tile, loops over ITER i's.
// 32x32x16 MFMA: M = 32 pairs (j), N = 32 outs, K = 64 hid (4 chunks of 16).
// Lane L: pair p = L&31, hid-slice k = c*16 + (L>>5)*8 + jj  (A-fragment layout).
// A rows / b1 / coords staged in LDS per block (kills s_load stalls); Edges
// software-pipelined; j-side invariants (Bj, W2 frags, cj, b2) in VGPRs.
__global__ __launch_bounds__(256, 4) void main_kernel(
    const float* __restrict__ Edges,
    const float* __restrict__ ws,
    float* __restrict__ out)
{
    __shared__ float lds[ITER * HID + HID + ITER * 4]; // A rows | b1 | ci rows

    const int t    = threadIdx.x;
    const int lane = t & 63;
    const int wave = t >> 6;
    const int j0   = blockIdx.x * 128 + wave * 32;
    const int i0   = blockIdx.y * ITER;
    const int p    = lane & 31;
    const int half = lane >> 5;
    const int jp   = j0 + p;

    // ---- stage LDS: A[i0..i0+7][64], b1[64], C4[i0..i0+7] ----
    {
        const float* srcA = ws + WS_A + (size_t)i0 * HID;   // 512 contiguous floats
        if (t < 128) {
            *(float4*)&lds[t * 4] = *(const float4*)(srcA + t * 4);
        } else if (t < 144) {
            *(float4*)&lds[ITER * HID + (t - 128) * 4] =
                *(const float4*)(ws + WS_B1 + (t - 128) * 4);
        } else if (t < 152) {
            *(float4*)&lds[ITER * HID + HID + (t - 144) * 4] =
                *(const float4*)(ws + WS_C4 + (size_t)(i0 + (t - 144)) * 4);
        }
    }

    // ---- loop-invariant state (VGPRs) ----
    const ushort* w2hp = (const ushort*)(ws + WS_W2H);
    bf16x8 bh[4];
    #pragma unroll
    for (int c = 0; c < 4; ++c)
        bh[c] = *(const bf16x8*)(w2hp + (c * 64 + lane) * 8);

    const float* __restrict__ Bj = ws + WS_B + (size_t)jp * HID;
    float bv[4][8];
    #pragma unroll
    for (int c = 0; c < 4; ++c) {
        const int h0 = c * 16 + half * 8;
        *(float4*)(&bv[c][0]) = *(const float4*)(Bj + h0);
        *(float4*)(&bv[c][4]) = *(const float4*)(Bj + h0 + 4);
    }
    const float4 cj  = *(const float4*)(ws + WS_C4 + (size_t)jp * 4);
    const float  b2n = ws[WS_B2 + p];

    __syncthreads();

    // Edges software pipeline
    const float* egp = Edges + (size_t)i0 * NN + jp;
    float eg = *egp;

    #pragma unroll 1
    for (int it = 0; it < ITER; ++it) {
        const int i = i0 + it;
        const float eg_cur = eg;
        if (it + 1 < ITER) eg = egp[(size_t)(it + 1) * NN];  // prefetch next row

        // ci via LDS broadcast (all lanes same addr = free)
        const float4 civ = *(const float4*)&lds[ITER * HID + HID + it * 4];
        const float dx = civ.x - cj.x, dy = civ.y - cj.y, dz = civ.z - cj.z;
        const float dist = sqrtf(dx * dx + dy * dy + dz * dz);
        const float w = eg_cur * dist;

        // layer-1 + swish; split h1 into truncated bf16 hi + exact-residual lo
        FragU ah[4], al[4];
        #pragma unroll
        for (int c = 0; c < 4; ++c) {
            const int ho = c * 16 + half * 8;
            float av[8], b1c[8];
            *(float4*)(av + 0)  = *(const float4*)&lds[it * HID + ho];
            *(float4*)(av + 4)  = *(const float4*)&lds[it * HID + ho + 4];
            *(float4*)(b1c + 0) = *(const float4*)&lds[ITER * HID + ho];
            *(float4*)(b1c + 4) = *(const float4*)&lds[ITER * HID + ho + 4];
            #pragma unroll
            for (int jj = 0; jj < 8; ++jj) {
                const float pre = fmaf(w, av[jj] + bv[c][jj], b1c[jj]);
                const float h1  = swish(pre);
                const uint  x   = __float_as_uint(h1);
                const float lo  = h1 - __uint_as_float(x & 0xffff0000u);
                ah[c].u[jj] = (ushort)(x >> 16);
                al[c].u[jj] = (ushort)(__float_as_uint(lo) >> 16);
            }
        }

        // layer-2 GEMM: pre2 = (h1_hi + h1_lo) @ W2hi^T   (8 MFMAs)
        floatx16 acc = {0.f,0.f,0.f,0.f,0.f,0.f,0.f,0.f,
                        0.f,0.f,0.f,0.f,0.f,0.f,0.f,0.f};
        #pragma unroll
        for (int c = 0; c < 4; ++c) {
            acc = __builtin_amdgcn_mfma_f32_32x32x16_bf16(ah[c].v, bh[c], acc, 0, 0, 0);
            acc = __builtin_amdgcn_mfma_f32_32x32x16_bf16(al[c].v, bh[c], acc, 0, 0, 0);
        }

        // epilogue: C/D layout n = lane&31, m = (r&3) + 8*(r>>2) + 4*half
        // nontemporal: streaming writes must not evict the L2 working set
        float* __restrict__ ob = out + ((size_t)i * NN + j0) * OUTF + p;
        #pragma unroll
        for (int r = 0; r < 16; ++r) {
            const int m = (r & 3) + 8 * (r >> 2) + 4 * half;
            __builtin_nontemporal_store(swish(acc[r] + b2n), ob + m * OUTF);
        }
    }
}

extern "C" void kernel_launch(void* const* d_in, const int* in_sizes, int n_in,
                              void* d_out, int out_size, void* d_ws, size_t ws_size,
                              hipStream_t stream)
{
    const float* Edges  = (const float*)d_in[0];
    const float* Coords = (const float*)d_in[1];
    const float* Emb    = (const float*)d_in[2];
    const float* W1     = (const float*)d_in[3];
    const float* b1     = (const float*)d_in[4];
    const float* W2     = (const float*)d_in[5];
    const float* b2     = (const float*)d_in[6];
    float* ws  = (float*)d_ws;
    float* out = (float*)d_out;

    hipLaunchKernelGGL(prep_kernel, dim3(NN + 1), dim3(64), 0, stream,
                       Coords, Emb, W1, b1, W2, b2, ws);
    hipLaunchKernelGGL(main_kernel, dim3(NN / 128, NN / ITER), dim3(256), 0, stream,
                       Edges, ws, out);
}